// Round 21
// baseline (154.031 us; speedup 1.0000x reference)
//
#include <hip/hip_runtime.h>
#include <hip/hip_bf16.h>
#include <math.h>

#define BLK 1024   // 16 waves/block; per-point staging + barrier cost halves
                   // again vs BLK=512 (R20). Per-thread MLP code unchanged.
#define TT  4096   // T0 = min(16^3, 2^19) = 4096 for every level
#define WSETS 36   // weight A-fragment sets in d_ws after the tables

typedef short bf16x8 __attribute__((ext_vector_type(8)));
typedef float f32x4  __attribute__((ext_vector_type(4)));

// Packed f32x2 -> bf16x2 RNE via native v_cvt_pk_bf16_f32 (memcpy, not
// bit_cast: __hip_bfloat162 is not trivially copyable on this ROCm).
__device__ __forceinline__ unsigned pk(float a, float b) {
  __hip_bfloat162 h = __float22bfloat162_rn(make_float2(a, b));
  unsigned r; __builtin_memcpy(&r, &h, sizeof(r));
  return r;
}
__device__ __forceinline__ bf16x8 mk8(unsigned w0, unsigned w1, unsigned w2, unsigned w3) {
  uint4 u; u.x = w0; u.y = w1; u.z = w2; u.w = w3;
  bf16x8 r; __builtin_memcpy(&r, &u, 16);
  return r;
}
__device__ __forceinline__ bf16x8 ld8(const uint4* __restrict__ wsW, int set, int lane) {
  uint4 u = wsW[set * 64 + lane];
  bf16x8 r; __builtin_memcpy(&r, &u, 16);
  return r;
}
__device__ __forceinline__ float bflo(unsigned w) {
  return __builtin_bit_cast(float, w << 16);
}
__device__ __forceinline__ float bfhi(unsigned w) {
  return __builtin_bit_cast(float, w & 0xFFFF0000u);
}
__device__ __forceinline__ f32x4 mfma16(bf16x8 a, bf16x8 b, f32x4 c) {
  return __builtin_amdgcn_mfma_f32_16x16x32_bf16(a, b, c, 0, 0, 0);
}

// ---- one-time prepack into d_ws: bf16 tables + weight A-fragments ----------
// Tables: word i = pk(emb[2i], emb[2i+1]), i in [0, 16*TT).
// Weights: set s, lane l=(q,p) -> uint4 = A[row=f][k=kt*32+8q+j], j=0..7.
// Sets: gw0 [0..3] | gw1 [4..11] | dw [12..13] | cw0' [14..17] | cw1 [18..25]
//       | cw2 [26..33] | rw [34..35].  Same RNE cvt as inline -> bit-identical.
__global__ void ngp_pack(const float* __restrict__ emb,
                         const float* __restrict__ gw0, const float* __restrict__ gw1,
                         const float* __restrict__ dw,  const float* __restrict__ cw0,
                         const float* __restrict__ cw1, const float* __restrict__ cw2,
                         const float* __restrict__ rw,  unsigned* __restrict__ ws)
{
  int i = blockIdx.x * blockDim.x + threadIdx.x;
  if (i < 16 * TT) {
    const float* s = emb + 2 * (size_t)i;
    ws[i] = pk(s[0], s[1]);
    return;
  }
  i -= 16 * TT;
  if (i >= WSETS * 64) return;
  int s = i >> 6, l = i & 63;
  int q = l >> 4, p = l & 15;

  const float* W; int out = 64, mt = 0, kt = 0, typ = 0;  // 1: cw0 shift; 2: rw pad
  if      (s < 4)  { W = gw0; mt = s; }
  else if (s < 12) { W = gw1; mt = (s - 4) >> 1;  kt = (s - 4) & 1; }
  else if (s < 14) { W = dw;  out = 16; kt = s - 12; }
  else if (s < 18) { W = cw0; mt = s - 14; typ = 1; }
  else if (s < 26) { W = cw1; mt = (s - 18) >> 1; kt = (s - 18) & 1; }
  else if (s < 34) { W = cw2; mt = (s - 26) >> 1; kt = (s - 26) & 1; }
  else             { W = rw;  out = 3; kt = s - 34; typ = 2; }
  int f = (out == 16) ? p : ((out == 3) ? p : mt * 16 + p);
  float v[8];
  #pragma unroll
  for (int j = 0; j < 8; ++j) {
    int k = kt * 32 + q * 8 + j;
    if (typ == 1)      v[j] = (k == 0) ? 0.0f : W[(k - 1) * 64 + f];
    else if (typ == 2) v[j] = (p < 3) ? W[k * 3 + p] : 0.0f;
    else               v[j] = W[k * out + f];
  }
  uint4 wv;
  wv.x = pk(v[0], v[1]); wv.y = pk(v[2], v[3]);
  wv.z = pk(v[4], v[5]); wv.w = pk(v[6], v[7]);
  ((uint4*)(ws + 16 * TT))[s * 64 + l] = wv;
}

// ---- B-fragment builders: pure cross-lane (R9/R10-proven) ------------------
// lane (q,p): A[row=p][k=32kt+8q+j]; B[k=32kt+8q+j][col=p]; D[row=4q+r][col=p].
__device__ __forceinline__ bf16x8 bfrag_pt(const unsigned (&ep)[16], int src, int q) {
  bf16x8 b;
  #pragma unroll
  for (int w = 0; w < 4; ++w) {
    int v0 = __shfl((int)ep[w],      src);
    int v1 = __shfl((int)ep[4 + w],  src);
    int v2 = __shfl((int)ep[8 + w],  src);
    int v3 = __shfl((int)ep[12 + w], src);
    int lo = (q & 1) ? v1 : v0;
    int hi = (q & 1) ? v3 : v2;
    unsigned word = (unsigned)((q & 2) ? hi : lo);
    b[2 * w]     = (short)(word & 0xFFFFu);
    b[2 * w + 1] = (short)(word >> 16);
  }
  return b;
}

template<int KT_>
__device__ __forceinline__ bf16x8 bfrag_u(const unsigned (&unt)[4][2], int q, int p) {
  bf16x8 b;
  #pragma unroll
  for (int w = 0; w < 4; ++w) {
    int src = (((2 * q + (w >> 1)) & 3) << 4) + p;
    int v0 = __shfl((int)unt[2 * KT_][w & 1],     src);
    int v1 = __shfl((int)unt[2 * KT_ + 1][w & 1], src);
    unsigned word = (unsigned)((q >> 1) ? v1 : v0);
    b[2 * w]     = (short)(word & 0xFFFFu);
    b[2 * w + 1] = (short)(word >> 16);
  }
  return b;
}

__device__ __forceinline__ bf16x8 bfrag_cat(const unsigned (&g2nt)[2], const unsigned (&shp)[8],
                                            int srcP, int q, int p) {
  bf16x8 b;
  #pragma unroll
  for (int w = 0; w < 4; ++w) {
    int srcG = (((2 * q + (w >> 1)) & 3) << 4) + p;
    int vg = __shfl((int)g2nt[w & 1], srcG);
    int v2 = __shfl((int)shp[w],      srcP);
    int v3 = __shfl((int)shp[4 + w],  srcP);
    unsigned word = (q < 2) ? (unsigned)vg : ((q == 2) ? (unsigned)v2 : (unsigned)v3);
    b[2 * w]     = (short)(word & 0xFFFFu);
    b[2 * w + 1] = (short)(word >> 16);
  }
  return b;
}

// ---- generic 64->64 layer; A from prepacked uint4 (PRE) or inline cvt ------
template<bool PRE, bool RELU>
__device__ __forceinline__ void layer64(const float* __restrict__ W, const uint4* __restrict__ wsW,
                                        int base, const float* __restrict__ bias,
                                        const unsigned (&uin)[4][4][2], unsigned (&uout)[4][4][2],
                                        int lane, int q, int p) {
  bf16x8 A[4][2];
  #pragma unroll
  for (int mt = 0; mt < 4; ++mt)
    #pragma unroll
    for (int kt = 0; kt < 2; ++kt) {
      if (PRE) {
        A[mt][kt] = ld8(wsW, base + mt * 2 + kt, lane);
      } else {
        const float* Wb = W + (kt * 32 + 8 * q) * 64 + mt * 16 + p;
        A[mt][kt] = mk8(pk(Wb[0 * 64], Wb[1 * 64]), pk(Wb[2 * 64], Wb[3 * 64]),
                        pk(Wb[4 * 64], Wb[5 * 64]), pk(Wb[6 * 64], Wb[7 * 64]));
      }
    }
  f32x4 bi[4];
  #pragma unroll
  for (int mt = 0; mt < 4; ++mt) bi[mt] = *(const f32x4*)(bias + mt * 16 + 4 * q);
  #pragma unroll
  for (int nt = 0; nt < 4; ++nt) {
    bf16x8 B0 = bfrag_u<0>(uin[nt], q, p);
    bf16x8 B1 = bfrag_u<1>(uin[nt], q, p);
    #pragma unroll
    for (int mt = 0; mt < 4; ++mt) {
      f32x4 acc = bi[mt];
      acc = mfma16(A[mt][0], B0, acc);
      acc = mfma16(A[mt][1], B1, acc);
      if (RELU) {
        acc.x = fmaxf(acc.x, 0.0f); acc.y = fmaxf(acc.y, 0.0f);
        acc.z = fmaxf(acc.z, 0.0f); acc.w = fmaxf(acc.w, 0.0f);
      }
      uout[nt][mt][0] = pk(acc.x, acc.y);
      uout[nt][mt][1] = pk(acc.z, acc.w);
    }
  }
}

template<bool PRE>
__global__ __launch_bounds__(BLK, 4)   // 16 waves/block, 4 waves/EU contract
void ngp_fused9(const float* __restrict__ pos,  const float* __restrict__ dirs,
                const float* __restrict__ emb,  const unsigned* __restrict__ wsTab,
                const float* __restrict__ gw0, const float* __restrict__ gb0,
                const float* __restrict__ gw1, const float* __restrict__ gb1,
                const float* __restrict__ dw,  const float* __restrict__ db,
                const float* __restrict__ cw0, const float* __restrict__ cb0,
                const float* __restrict__ cw1, const float* __restrict__ cb1,
                const float* __restrict__ cw2, const float* __restrict__ cb2,
                const float* __restrict__ rw,  const float* __restrict__ rb,
                float* __restrict__ outd, float* __restrict__ outrgb, int N)
{
  // Double-buffered bf16 hash-table stage: 2 x 16 KB (R10..R20-proven).
  // At BLK=1024 each thread stages 1 uint4 per level.
  __shared__ unsigned tab[2][TT];

  const int tid  = threadIdx.x;
  const int lane = tid & 63, wave = tid >> 6;
  const int q = lane >> 4, p = lane & 15;
  const int idx = blockIdx.x * BLK + tid;
  const int ic = min(idx, N - 1);
  const int ptb = blockIdx.x * BLK + wave * 64;
  const uint4* wsW = (const uint4*)(wsTab + 16 * TT);

  const float pnx = pos[3 * ic + 0] * 0.5f;   // pn = positions / BOUND
  const float pny = pos[3 * ic + 1] * 0.5f;
  const float pnz = pos[3 * ic + 2] * 0.5f;

  auto stage = [&](int li) {
    if (PRE) {
      const uint4* s4 = (const uint4*)(wsTab + (size_t)li * TT);
      uint4* dst = (uint4*)tab[li & 1];
      #pragma unroll
      for (int j = 0; j < (TT / 4) / BLK; ++j)         // 1 iter at BLK=1024
        dst[tid + j * BLK] = s4[tid + j * BLK];
    } else {
      const f32x4* s4 = (const f32x4*)(emb + (size_t)li * (TT * 2));
      uint2* dst = (uint2*)tab[li & 1];
      #pragma unroll
      for (int j = 0; j < (TT / 2) / BLK; ++j) {
        f32x4 v = s4[tid + j * BLK];
        uint2 w; w.x = pk(v.x, v.y); w.y = pk(v.z, v.w);
        dst[tid + j * BLK] = w;
      }
    }
  };

  float enc[32];
  stage(0);
  __syncthreads();
  #pragma unroll
  for (int li = 0; li < 16; ++li) {
    if (li < 15) stage(li + 1);                        // write OTHER buffer
    const unsigned* t = tab[li & 1];
    const int   res = 16 << li;
    const float rm1 = (float)(res - 1);
    float sx = (pnx + 1.0f) * 0.5f * rm1;
    float sy = (pny + 1.0f) * 0.5f * rm1;
    float sz = (pnz + 1.0f) * 0.5f * rm1;
    float fx = floorf(sx), fy = floorf(sy), fz = floorf(sz);
    float wx = sx - fx,    wy = sy - fy,    wz = sz - fz;
    int ix = (int)fx, iy = (int)fy, iz = (int)fz;
    int x0 = min(max(ix, 0),     res - 1), x1 = min(max(ix + 1, 0), res - 1);
    int y0 = min(max(iy, 0),     res - 1), y1 = min(max(iy + 1, 0), res - 1);
    int z0 = min(max(iz, 0),     res - 1), z1 = min(max(iz + 1, 0), res - 1);
    unsigned a0 = (unsigned)x0,         a1 = (unsigned)x1;
    unsigned b0 = (unsigned)y0 * 2481u, b1 = (unsigned)y1 * 2481u;
    unsigned d0 = (unsigned)z0 * 1941u, d1 = (unsigned)z1 * 1941u;
    unsigned w0 = t[(a0 ^ b0 ^ d0) & 4095u];
    unsigned w1 = t[(a0 ^ b0 ^ d1) & 4095u];
    unsigned w2 = t[(a0 ^ b1 ^ d0) & 4095u];
    unsigned w3 = t[(a0 ^ b1 ^ d1) & 4095u];
    unsigned w4 = t[(a1 ^ b0 ^ d0) & 4095u];
    unsigned w5 = t[(a1 ^ b0 ^ d1) & 4095u];
    unsigned w6 = t[(a1 ^ b1 ^ d0) & 4095u];
    unsigned w7 = t[(a1 ^ b1 ^ d1) & 4095u];
    // replicate reference's literal blend axis order (wx on dz-pairs)
    float omx = 1.0f - wx, omy = 1.0f - wy, omz = 1.0f - wz;
    float c00x = bflo(w0) * omx + bflo(w1) * wx, c00y = bfhi(w0) * omx + bfhi(w1) * wx;
    float c01x = bflo(w2) * omx + bflo(w3) * wx, c01y = bfhi(w2) * omx + bfhi(w3) * wx;
    float c10x = bflo(w4) * omx + bflo(w5) * wx, c10y = bfhi(w4) * omx + bfhi(w5) * wx;
    float c11x = bflo(w6) * omx + bflo(w7) * wx, c11y = bfhi(w6) * omx + bfhi(w7) * wx;
    float e0x = c00x * omy + c01x * wy,  e0y = c00y * omy + c01y * wy;
    float e1x = c10x * omy + c11x * wy,  e1y = c10y * omy + c11y * wy;
    enc[2 * li + 0] = e0x * omz + e1x * wz;
    enc[2 * li + 1] = e0y * omz + e1y * wz;
    __syncthreads();   // gathers(li) done; stage(li+1) complete for next iter
  }
  unsigned encp[16];
  #pragma unroll
  for (int m = 0; m < 16; ++m) encp[m] = pk(enc[2 * m], enc[2 * m + 1]);

  // ---- SH16 of own direction, packed to 8 words ---------------------------
  unsigned shp[8];
  {
    float ddx = dirs[3 * ic + 0], ddy = dirs[3 * ic + 1], ddz = dirs[3 * ic + 2];
    float nrm = fmaxf(sqrtf(ddx * ddx + ddy * ddy + ddz * ddz), 1e-12f);
    float x = ddx / nrm, y = ddy / nrm, z = ddz / nrm;
    float xx = x * x, yy = y * y, zz = z * z;
    float xy = x * y, yz = y * z, xz = x * z;
    float sh0  = 0.28209479177387814f;
    float sh1  = -0.48860251190291987f * y;
    float sh2  =  0.48860251190291987f * z;
    float sh3  = -0.48860251190291987f * x;
    float sh4  =  1.0925484305920792f * xy;
    float sh5  = -1.0925484305920792f * yz;
    float sh6  =  0.31539156525252005f * (2.0f * zz - xx - yy);
    float sh7  = -1.0925484305920792f * xz;
    float sh8  =  0.5462742152960396f * (xx - yy);
    float sh9  = -0.5900435899266435f * y * (3.0f * xx - yy);
    float sh10 =  2.890611442640554f * xy * z;
    float sh11 = -0.4570457994644658f * y * (4.0f * zz - xx - yy);
    float sh12 =  0.3731763325901154f * z * (2.0f * zz - 3.0f * xx - 3.0f * yy);
    float sh13 = -0.4570457994644658f * x * (4.0f * zz - xx - yy);
    float sh14 =  1.445305721320277f * z * (xx - yy);
    float sh15 = -0.5900435899266435f * x * (xx - 3.0f * yy);
    shp[0] = pk(sh0,  sh1);  shp[1] = pk(sh2,  sh3);
    shp[2] = pk(sh4,  sh5);  shp[3] = pk(sh6,  sh7);
    shp[4] = pk(sh8,  sh9);  shp[5] = pk(sh10, sh11);
    shp[6] = pk(sh12, sh13); shp[7] = pk(sh14, sh15);
  }

  unsigned uA[4][4][2], uB[4][4][2];

  { // L0: enc(32) -> 64, relu.  A = sets 0..3 (or inline gw0 pair-convert).
    bf16x8 A[4];
    #pragma unroll
    for (int mt = 0; mt < 4; ++mt) {
      if (PRE) {
        A[mt] = ld8(wsW, mt, lane);
      } else {
        const float* Wb = gw0 + (8 * q) * 64 + mt * 16 + p;
        A[mt] = mk8(pk(Wb[0 * 64], Wb[1 * 64]), pk(Wb[2 * 64], Wb[3 * 64]),
                    pk(Wb[4 * 64], Wb[5 * 64]), pk(Wb[6 * 64], Wb[7 * 64]));
      }
    }
    f32x4 bi[4];
    #pragma unroll
    for (int mt = 0; mt < 4; ++mt) bi[mt] = *(const f32x4*)(gb0 + mt * 16 + 4 * q);
    #pragma unroll
    for (int nt = 0; nt < 4; ++nt) {
      bf16x8 B = bfrag_pt(encp, nt * 16 + p, q);
      #pragma unroll
      for (int mt = 0; mt < 4; ++mt) {
        f32x4 acc = mfma16(A[mt], B, bi[mt]);
        acc.x = fmaxf(acc.x, 0.0f); acc.y = fmaxf(acc.y, 0.0f);
        acc.z = fmaxf(acc.z, 0.0f); acc.w = fmaxf(acc.w, 0.0f);
        uA[nt][mt][0] = pk(acc.x, acc.y);
        uA[nt][mt][1] = pk(acc.z, acc.w);
      }
    }
  }

  layer64<PRE, true>(gw1, wsW, 4, gb1, uA, uB, lane, q, p);   // L1: 64->64, relu

  unsigned g2[4][2];
  { // L2: 64 -> 16 (dw), no relu; density out.  A = sets 12..13.
    bf16x8 A[2];
    #pragma unroll
    for (int kt = 0; kt < 2; ++kt) {
      if (PRE) {
        A[kt] = ld8(wsW, 12 + kt, lane);
      } else {
        const float* Wb = dw + (kt * 32 + 8 * q) * 16 + p;
        A[kt] = mk8(pk(Wb[0 * 16], Wb[1 * 16]), pk(Wb[2 * 16], Wb[3 * 16]),
                    pk(Wb[4 * 16], Wb[5 * 16]), pk(Wb[6 * 16], Wb[7 * 16]));
      }
    }
    f32x4 bi = *(const f32x4*)(db + 4 * q);
    #pragma unroll
    for (int nt = 0; nt < 4; ++nt) {
      bf16x8 B0 = bfrag_u<0>(uB[nt], q, p);
      bf16x8 B1 = bfrag_u<1>(uB[nt], q, p);
      f32x4 acc = mfma16(A[0], B0, bi);
      acc = mfma16(A[1], B1, acc);
      if (q == 0) {                 // g[0] = row 0 -> lane (0,p), acc.x
        int pt = ptb + nt * 16 + p;
        if (pt < N) outd[pt] = expf(acc.x - 1.0f);
      }
      g2[nt][0] = pk(acc.x, acc.y);
      g2[nt][1] = pk(acc.z, acc.w);
    }
  }

  { // L3: concat(g[1:16], sh16) -> 64, relu.  A = sets 14..17 (k-shifted cw0).
    bf16x8 A[4];
    #pragma unroll
    for (int mt = 0; mt < 4; ++mt) {
      if (PRE) {
        A[mt] = ld8(wsW, 14 + mt, lane);
      } else {
        float v[8];
        #pragma unroll
        for (int j = 0; j < 8; ++j) {
          int k = 8 * q + j;
          v[j] = (k == 0) ? 0.0f : cw0[(k - 1) * 64 + mt * 16 + p];
        }
        A[mt] = mk8(pk(v[0], v[1]), pk(v[2], v[3]), pk(v[4], v[5]), pk(v[6], v[7]));
      }
    }
    f32x4 bi[4];
    #pragma unroll
    for (int mt = 0; mt < 4; ++mt) bi[mt] = *(const f32x4*)(cb0 + mt * 16 + 4 * q);
    #pragma unroll
    for (int nt = 0; nt < 4; ++nt) {
      bf16x8 B = bfrag_cat(g2[nt], shp, nt * 16 + p, q, p);
      #pragma unroll
      for (int mt = 0; mt < 4; ++mt) {
        f32x4 acc = mfma16(A[mt], B, bi[mt]);
        acc.x = fmaxf(acc.x, 0.0f); acc.y = fmaxf(acc.y, 0.0f);
        acc.z = fmaxf(acc.z, 0.0f); acc.w = fmaxf(acc.w, 0.0f);
        uA[nt][mt][0] = pk(acc.x, acc.y);
        uA[nt][mt][1] = pk(acc.z, acc.w);
      }
    }
  }

  layer64<PRE, false>(cw1, wsW, 18, cb1, uA, uB, lane, q, p); // L4: 64->64
  layer64<PRE, false>(cw2, wsW, 26, cb2, uB, uA, lane, q, p); // L5: 64->64

  { // L6: 64 -> 3 (rw), sigmoid out.  A = sets 34..35 (rows >=3 zeroed).
    bf16x8 A[2];
    #pragma unroll
    for (int kt = 0; kt < 2; ++kt) {
      if (PRE) {
        A[kt] = ld8(wsW, 34 + kt, lane);
      } else {
        float v[8];
        #pragma unroll
        for (int j = 0; j < 8; ++j) {
          int k = kt * 32 + 8 * q + j;
          v[j] = (p < 3) ? rw[k * 3 + p] : 0.0f;
        }
        A[kt] = mk8(pk(v[0], v[1]), pk(v[2], v[3]), pk(v[4], v[5]), pk(v[6], v[7]));
      }
    }
    float r0 = rb[0], r1 = rb[1], r2 = rb[2];
    #pragma unroll
    for (int nt = 0; nt < 4; ++nt) {
      bf16x8 B0 = bfrag_u<0>(uA[nt], q, p);
      bf16x8 B1 = bfrag_u<1>(uA[nt], q, p);
      f32x4 acc;
      acc.x = (q == 0) ? r0 : 0.0f;
      acc.y = (q == 0) ? r1 : 0.0f;
      acc.z = (q == 0) ? r2 : 0.0f;
      acc.w = 0.0f;
      acc = mfma16(A[0], B0, acc);
      acc = mfma16(A[1], B1, acc);
      if (q == 0) {                 // rgb = rows 0..2 -> lane (0,p): acc.x/y/z
        int pt = ptb + nt * 16 + p;
        if (pt < N) {
          outrgb[3 * pt + 0] = 1.0f / (1.0f + expf(-acc.x));
          outrgb[3 * pt + 1] = 1.0f / (1.0f + expf(-acc.y));
          outrgb[3 * pt + 2] = 1.0f / (1.0f + expf(-acc.z));
        }
      }
    }
  }
}

extern "C" void kernel_launch(void* const* d_in, const int* in_sizes, int n_in,
                              void* d_out, int out_size, void* d_ws, size_t ws_size,
                              hipStream_t stream) {
  const float* pos  = (const float*)d_in[0];
  const float* dirs = (const float*)d_in[1];
  const float* emb  = (const float*)d_in[2];
  const float* gw0  = (const float*)d_in[3];
  const float* gb0  = (const float*)d_in[4];
  const float* gw1  = (const float*)d_in[5];
  const float* gb1  = (const float*)d_in[6];
  const float* dw   = (const float*)d_in[7];
  const float* db   = (const float*)d_in[8];
  const float* cw0  = (const float*)d_in[9];
  const float* cb0  = (const float*)d_in[10];
  const float* cw1  = (const float*)d_in[11];
  const float* cb1  = (const float*)d_in[12];
  const float* cw2  = (const float*)d_in[13];
  const float* cb2  = (const float*)d_in[14];
  const float* rw   = (const float*)d_in[15];
  const float* rb   = (const float*)d_in[16];

  const int N = in_sizes[0] / 3;
  float* outd   = (float*)d_out;
  float* outrgb = outd + N;

  const size_t need = (size_t)(16 * TT) * 4 + (size_t)(WSETS * 64) * 16; // 299008 B
  const bool pre = (ws_size >= need);
  unsigned* wsTab = (unsigned*)d_ws;

  const int grid = (N + BLK - 1) / BLK;
  if (pre) {
    const int packN = 16 * TT + WSETS * 64;
    hipLaunchKernelGGL(ngp_pack, dim3((packN + 255) / 256), dim3(256), 0, stream,
                       emb, gw0, gw1, dw, cw0, cw1, cw2, rw, wsTab);
    hipLaunchKernelGGL((ngp_fused9<true>), dim3(grid), dim3(BLK), 0, stream,
                       pos, dirs, emb, wsTab, gw0, gb0, gw1, gb1, dw, db,
                       cw0, cb0, cw1, cb1, cw2, cb2, rw, rb, outd, outrgb, N);
  } else {
    hipLaunchKernelGGL((ngp_fused9<false>), dim3(grid), dim3(BLK), 0, stream,
                       pos, dirs, emb, wsTab, gw0, gb0, gw1, gb1, dw, db,
                       cw0, cb0, cw1, cb1, cw2, cb2, rw, rb, outd, outrgb, N);
  }
}

// Round 22
// 152.326 us; speedup vs baseline: 1.0112x; 1.0112x over previous
//
#include <hip/hip_runtime.h>
#include <hip/hip_bf16.h>
#include <math.h>

#define BLK 512    // 8 waves/block: measured optimum (R20 152.8us; 256->162us,
                   // 1024->154us). Per-point staging+barrier amortization.
#define TT  4096   // T0 = min(16^3, 2^19) = 4096 for every level
#define WSETS 36   // weight A-fragment sets in d_ws after the tables

typedef short bf16x8 __attribute__((ext_vector_type(8)));
typedef float f32x4  __attribute__((ext_vector_type(4)));

// Packed f32x2 -> bf16x2 RNE via native v_cvt_pk_bf16_f32 (memcpy, not
// bit_cast: __hip_bfloat162 is not trivially copyable on this ROCm).
__device__ __forceinline__ unsigned pk(float a, float b) {
  __hip_bfloat162 h = __float22bfloat162_rn(make_float2(a, b));
  unsigned r; __builtin_memcpy(&r, &h, sizeof(r));
  return r;
}
__device__ __forceinline__ bf16x8 mk8(unsigned w0, unsigned w1, unsigned w2, unsigned w3) {
  uint4 u; u.x = w0; u.y = w1; u.z = w2; u.w = w3;
  bf16x8 r; __builtin_memcpy(&r, &u, 16);
  return r;
}
__device__ __forceinline__ bf16x8 ld8(const uint4* __restrict__ wsW, int set, int lane) {
  uint4 u = wsW[set * 64 + lane];
  bf16x8 r; __builtin_memcpy(&r, &u, 16);
  return r;
}
__device__ __forceinline__ float bflo(unsigned w) {
  return __builtin_bit_cast(float, w << 16);
}
__device__ __forceinline__ float bfhi(unsigned w) {
  return __builtin_bit_cast(float, w & 0xFFFF0000u);
}
__device__ __forceinline__ f32x4 mfma16(bf16x8 a, bf16x8 b, f32x4 c) {
  return __builtin_amdgcn_mfma_f32_16x16x32_bf16(a, b, c, 0, 0, 0);
}

// ---- one-time prepack into d_ws: bf16 tables + weight A-fragments ----------
// Tables: word i = pk(emb[2i], emb[2i+1]), i in [0, 16*TT).
// Weights: set s, lane l=(q,p) -> uint4 = A[row=f][k=kt*32+8q+j], j=0..7.
// Sets: gw0 [0..3] | gw1 [4..11] | dw [12..13] | cw0' [14..17] | cw1 [18..25]
//       | cw2 [26..33] | rw [34..35].  Same RNE cvt as inline -> bit-identical.
__global__ void ngp_pack(const float* __restrict__ emb,
                         const float* __restrict__ gw0, const float* __restrict__ gw1,
                         const float* __restrict__ dw,  const float* __restrict__ cw0,
                         const float* __restrict__ cw1, const float* __restrict__ cw2,
                         const float* __restrict__ rw,  unsigned* __restrict__ ws)
{
  int i = blockIdx.x * blockDim.x + threadIdx.x;
  if (i < 16 * TT) {
    const float* s = emb + 2 * (size_t)i;
    ws[i] = pk(s[0], s[1]);
    return;
  }
  i -= 16 * TT;
  if (i >= WSETS * 64) return;
  int s = i >> 6, l = i & 63;
  int q = l >> 4, p = l & 15;

  const float* W; int out = 64, mt = 0, kt = 0, typ = 0;  // 1: cw0 shift; 2: rw pad
  if      (s < 4)  { W = gw0; mt = s; }
  else if (s < 12) { W = gw1; mt = (s - 4) >> 1;  kt = (s - 4) & 1; }
  else if (s < 14) { W = dw;  out = 16; kt = s - 12; }
  else if (s < 18) { W = cw0; mt = s - 14; typ = 1; }
  else if (s < 26) { W = cw1; mt = (s - 18) >> 1; kt = (s - 18) & 1; }
  else if (s < 34) { W = cw2; mt = (s - 26) >> 1; kt = (s - 26) & 1; }
  else             { W = rw;  out = 3; kt = s - 34; typ = 2; }
  int f = (out == 16) ? p : ((out == 3) ? p : mt * 16 + p);
  float v[8];
  #pragma unroll
  for (int j = 0; j < 8; ++j) {
    int k = kt * 32 + q * 8 + j;
    if (typ == 1)      v[j] = (k == 0) ? 0.0f : W[(k - 1) * 64 + f];
    else if (typ == 2) v[j] = (p < 3) ? W[k * 3 + p] : 0.0f;
    else               v[j] = W[k * out + f];
  }
  uint4 wv;
  wv.x = pk(v[0], v[1]); wv.y = pk(v[2], v[3]);
  wv.z = pk(v[4], v[5]); wv.w = pk(v[6], v[7]);
  ((uint4*)(ws + 16 * TT))[s * 64 + l] = wv;
}

// ---- B-fragment builders: pure cross-lane (R9/R10-proven) ------------------
// lane (q,p): A[row=p][k=32kt+8q+j]; B[k=32kt+8q+j][col=p]; D[row=4q+r][col=p].
__device__ __forceinline__ bf16x8 bfrag_pt(const unsigned (&ep)[16], int src, int q) {
  bf16x8 b;
  #pragma unroll
  for (int w = 0; w < 4; ++w) {
    int v0 = __shfl((int)ep[w],      src);
    int v1 = __shfl((int)ep[4 + w],  src);
    int v2 = __shfl((int)ep[8 + w],  src);
    int v3 = __shfl((int)ep[12 + w], src);
    int lo = (q & 1) ? v1 : v0;
    int hi = (q & 1) ? v3 : v2;
    unsigned word = (unsigned)((q & 2) ? hi : lo);
    b[2 * w]     = (short)(word & 0xFFFFu);
    b[2 * w + 1] = (short)(word >> 16);
  }
  return b;
}

template<int KT_>
__device__ __forceinline__ bf16x8 bfrag_u(const unsigned (&unt)[4][2], int q, int p) {
  bf16x8 b;
  #pragma unroll
  for (int w = 0; w < 4; ++w) {
    int src = (((2 * q + (w >> 1)) & 3) << 4) + p;
    int v0 = __shfl((int)unt[2 * KT_][w & 1],     src);
    int v1 = __shfl((int)unt[2 * KT_ + 1][w & 1], src);
    unsigned word = (unsigned)((q >> 1) ? v1 : v0);
    b[2 * w]     = (short)(word & 0xFFFFu);
    b[2 * w + 1] = (short)(word >> 16);
  }
  return b;
}

__device__ __forceinline__ bf16x8 bfrag_cat(const unsigned (&g2nt)[2], const unsigned (&shp)[8],
                                            int srcP, int q, int p) {
  bf16x8 b;
  #pragma unroll
  for (int w = 0; w < 4; ++w) {
    int srcG = (((2 * q + (w >> 1)) & 3) << 4) + p;
    int vg = __shfl((int)g2nt[w & 1], srcG);
    int v2 = __shfl((int)shp[w],      srcP);
    int v3 = __shfl((int)shp[4 + w],  srcP);
    unsigned word = (q < 2) ? (unsigned)vg : ((q == 2) ? (unsigned)v2 : (unsigned)v3);
    b[2 * w]     = (short)(word & 0xFFFFu);
    b[2 * w + 1] = (short)(word >> 16);
  }
  return b;
}

// ---- generic 64->64 layer; A from prepacked uint4 (PRE) or inline cvt ------
template<bool PRE, bool RELU>
__device__ __forceinline__ void layer64(const float* __restrict__ W, const uint4* __restrict__ wsW,
                                        int base, const float* __restrict__ bias,
                                        const unsigned (&uin)[4][4][2], unsigned (&uout)[4][4][2],
                                        int lane, int q, int p) {
  bf16x8 A[4][2];
  #pragma unroll
  for (int mt = 0; mt < 4; ++mt)
    #pragma unroll
    for (int kt = 0; kt < 2; ++kt) {
      if (PRE) {
        A[mt][kt] = ld8(wsW, base + mt * 2 + kt, lane);
      } else {
        const float* Wb = W + (kt * 32 + 8 * q) * 64 + mt * 16 + p;
        A[mt][kt] = mk8(pk(Wb[0 * 64], Wb[1 * 64]), pk(Wb[2 * 64], Wb[3 * 64]),
                        pk(Wb[4 * 64], Wb[5 * 64]), pk(Wb[6 * 64], Wb[7 * 64]));
      }
    }
  f32x4 bi[4];
  #pragma unroll
  for (int mt = 0; mt < 4; ++mt) bi[mt] = *(const f32x4*)(bias + mt * 16 + 4 * q);
  #pragma unroll
  for (int nt = 0; nt < 4; ++nt) {
    bf16x8 B0 = bfrag_u<0>(uin[nt], q, p);
    bf16x8 B1 = bfrag_u<1>(uin[nt], q, p);
    #pragma unroll
    for (int mt = 0; mt < 4; ++mt) {
      f32x4 acc = bi[mt];
      acc = mfma16(A[mt][0], B0, acc);
      acc = mfma16(A[mt][1], B1, acc);
      if (RELU) {
        acc.x = fmaxf(acc.x, 0.0f); acc.y = fmaxf(acc.y, 0.0f);
        acc.z = fmaxf(acc.z, 0.0f); acc.w = fmaxf(acc.w, 0.0f);
      }
      uout[nt][mt][0] = pk(acc.x, acc.y);
      uout[nt][mt][1] = pk(acc.z, acc.w);
    }
  }
}

template<bool PRE>
__global__ __launch_bounds__(BLK, 4)   // 8 waves/block, 4 waves/EU -> 2 blocks/CU
void ngp_fused9(const float* __restrict__ pos,  const float* __restrict__ dirs,
                const float* __restrict__ emb,  const unsigned* __restrict__ wsTab,
                const float* __restrict__ gw0, const float* __restrict__ gb0,
                const float* __restrict__ gw1, const float* __restrict__ gb1,
                const float* __restrict__ dw,  const float* __restrict__ db,
                const float* __restrict__ cw0, const float* __restrict__ cb0,
                const float* __restrict__ cw1, const float* __restrict__ cb1,
                const float* __restrict__ cw2, const float* __restrict__ cb2,
                const float* __restrict__ rw,  const float* __restrict__ rb,
                float* __restrict__ outd, float* __restrict__ outrgb, int N)
{
  // Double-buffered bf16 hash-table stage: 2 x 16 KB (R10..R20-proven).
  __shared__ unsigned tab[2][TT];

  const int tid  = threadIdx.x;
  const int lane = tid & 63, wave = tid >> 6;
  const int q = lane >> 4, p = lane & 15;
  const int idx = blockIdx.x * BLK + tid;
  const int ic = min(idx, N - 1);
  const int ptb = blockIdx.x * BLK + wave * 64;
  const uint4* wsW = (const uint4*)(wsTab + 16 * TT);

  const float pnx = pos[3 * ic + 0] * 0.5f;   // pn = positions / BOUND
  const float pny = pos[3 * ic + 1] * 0.5f;
  const float pnz = pos[3 * ic + 2] * 0.5f;

  auto stage = [&](int li) {
    if (PRE) {
      const uint4* s4 = (const uint4*)(wsTab + (size_t)li * TT);
      uint4* dst = (uint4*)tab[li & 1];
      #pragma unroll
      for (int j = 0; j < (TT / 4) / BLK; ++j)         // 2 iters at BLK=512
        dst[tid + j * BLK] = s4[tid + j * BLK];
    } else {
      const f32x4* s4 = (const f32x4*)(emb + (size_t)li * (TT * 2));
      uint2* dst = (uint2*)tab[li & 1];
      #pragma unroll
      for (int j = 0; j < (TT / 2) / BLK; ++j) {
        f32x4 v = s4[tid + j * BLK];
        uint2 w; w.x = pk(v.x, v.y); w.y = pk(v.z, v.w);
        dst[tid + j * BLK] = w;
      }
    }
  };

  float enc[32];
  stage(0);
  __syncthreads();
  #pragma unroll
  for (int li = 0; li < 16; ++li) {
    if (li < 15) stage(li + 1);                        // write OTHER buffer
    const unsigned* t = tab[li & 1];
    const int   res = 16 << li;
    const float rm1 = (float)(res - 1);
    float sx = (pnx + 1.0f) * 0.5f * rm1;
    float sy = (pny + 1.0f) * 0.5f * rm1;
    float sz = (pnz + 1.0f) * 0.5f * rm1;
    float fx = floorf(sx), fy = floorf(sy), fz = floorf(sz);
    float wx = sx - fx,    wy = sy - fy,    wz = sz - fz;
    int ix = (int)fx, iy = (int)fy, iz = (int)fz;
    int x0 = min(max(ix, 0),     res - 1), x1 = min(max(ix + 1, 0), res - 1);
    int y0 = min(max(iy, 0),     res - 1), y1 = min(max(iy + 1, 0), res - 1);
    int z0 = min(max(iz, 0),     res - 1), z1 = min(max(iz + 1, 0), res - 1);
    unsigned a0 = (unsigned)x0,         a1 = (unsigned)x1;
    unsigned b0 = (unsigned)y0 * 2481u, b1 = (unsigned)y1 * 2481u;
    unsigned d0 = (unsigned)z0 * 1941u, d1 = (unsigned)z1 * 1941u;
    unsigned w0 = t[(a0 ^ b0 ^ d0) & 4095u];
    unsigned w1 = t[(a0 ^ b0 ^ d1) & 4095u];
    unsigned w2 = t[(a0 ^ b1 ^ d0) & 4095u];
    unsigned w3 = t[(a0 ^ b1 ^ d1) & 4095u];
    unsigned w4 = t[(a1 ^ b0 ^ d0) & 4095u];
    unsigned w5 = t[(a1 ^ b0 ^ d1) & 4095u];
    unsigned w6 = t[(a1 ^ b1 ^ d0) & 4095u];
    unsigned w7 = t[(a1 ^ b1 ^ d1) & 4095u];
    // replicate reference's literal blend axis order (wx on dz-pairs)
    float omx = 1.0f - wx, omy = 1.0f - wy, omz = 1.0f - wz;
    float c00x = bflo(w0) * omx + bflo(w1) * wx, c00y = bfhi(w0) * omx + bfhi(w1) * wx;
    float c01x = bflo(w2) * omx + bflo(w3) * wx, c01y = bfhi(w2) * omx + bfhi(w3) * wx;
    float c10x = bflo(w4) * omx + bflo(w5) * wx, c10y = bfhi(w4) * omx + bfhi(w5) * wx;
    float c11x = bflo(w6) * omx + bflo(w7) * wx, c11y = bfhi(w6) * omx + bfhi(w7) * wx;
    float e0x = c00x * omy + c01x * wy,  e0y = c00y * omy + c01y * wy;
    float e1x = c10x * omy + c11x * wy,  e1y = c10y * omy + c11y * wy;
    enc[2 * li + 0] = e0x * omz + e1x * wz;
    enc[2 * li + 1] = e0y * omz + e1y * wz;
    __syncthreads();   // gathers(li) done; stage(li+1) complete for next iter
  }
  unsigned encp[16];
  #pragma unroll
  for (int m = 0; m < 16; ++m) encp[m] = pk(enc[2 * m], enc[2 * m + 1]);

  // ---- SH16 of own direction, packed to 8 words ---------------------------
  unsigned shp[8];
  {
    float ddx = dirs[3 * ic + 0], ddy = dirs[3 * ic + 1], ddz = dirs[3 * ic + 2];
    float nrm = fmaxf(sqrtf(ddx * ddx + ddy * ddy + ddz * ddz), 1e-12f);
    float x = ddx / nrm, y = ddy / nrm, z = ddz / nrm;
    float xx = x * x, yy = y * y, zz = z * z;
    float xy = x * y, yz = y * z, xz = x * z;
    float sh0  = 0.28209479177387814f;
    float sh1  = -0.48860251190291987f * y;
    float sh2  =  0.48860251190291987f * z;
    float sh3  = -0.48860251190291987f * x;
    float sh4  =  1.0925484305920792f * xy;
    float sh5  = -1.0925484305920792f * yz;
    float sh6  =  0.31539156525252005f * (2.0f * zz - xx - yy);
    float sh7  = -1.0925484305920792f * xz;
    float sh8  =  0.5462742152960396f * (xx - yy);
    float sh9  = -0.5900435899266435f * y * (3.0f * xx - yy);
    float sh10 =  2.890611442640554f * xy * z;
    float sh11 = -0.4570457994644658f * y * (4.0f * zz - xx - yy);
    float sh12 =  0.3731763325901154f * z * (2.0f * zz - 3.0f * xx - 3.0f * yy);
    float sh13 = -0.4570457994644658f * x * (4.0f * zz - xx - yy);
    float sh14 =  1.445305721320277f * z * (xx - yy);
    float sh15 = -0.5900435899266435f * x * (xx - 3.0f * yy);
    shp[0] = pk(sh0,  sh1);  shp[1] = pk(sh2,  sh3);
    shp[2] = pk(sh4,  sh5);  shp[3] = pk(sh6,  sh7);
    shp[4] = pk(sh8,  sh9);  shp[5] = pk(sh10, sh11);
    shp[6] = pk(sh12, sh13); shp[7] = pk(sh14, sh15);
  }

  unsigned uA[4][4][2], uB[4][4][2];

  { // L0: enc(32) -> 64, relu.  A = sets 0..3 (or inline gw0 pair-convert).
    bf16x8 A[4];
    #pragma unroll
    for (int mt = 0; mt < 4; ++mt) {
      if (PRE) {
        A[mt] = ld8(wsW, mt, lane);
      } else {
        const float* Wb = gw0 + (8 * q) * 64 + mt * 16 + p;
        A[mt] = mk8(pk(Wb[0 * 64], Wb[1 * 64]), pk(Wb[2 * 64], Wb[3 * 64]),
                    pk(Wb[4 * 64], Wb[5 * 64]), pk(Wb[6 * 64], Wb[7 * 64]));
      }
    }
    f32x4 bi[4];
    #pragma unroll
    for (int mt = 0; mt < 4; ++mt) bi[mt] = *(const f32x4*)(gb0 + mt * 16 + 4 * q);
    #pragma unroll
    for (int nt = 0; nt < 4; ++nt) {
      bf16x8 B = bfrag_pt(encp, nt * 16 + p, q);
      #pragma unroll
      for (int mt = 0; mt < 4; ++mt) {
        f32x4 acc = mfma16(A[mt], B, bi[mt]);
        acc.x = fmaxf(acc.x, 0.0f); acc.y = fmaxf(acc.y, 0.0f);
        acc.z = fmaxf(acc.z, 0.0f); acc.w = fmaxf(acc.w, 0.0f);
        uA[nt][mt][0] = pk(acc.x, acc.y);
        uA[nt][mt][1] = pk(acc.z, acc.w);
      }
    }
  }

  layer64<PRE, true>(gw1, wsW, 4, gb1, uA, uB, lane, q, p);   // L1: 64->64, relu

  unsigned g2[4][2];
  { // L2: 64 -> 16 (dw), no relu; density out.  A = sets 12..13.
    bf16x8 A[2];
    #pragma unroll
    for (int kt = 0; kt < 2; ++kt) {
      if (PRE) {
        A[kt] = ld8(wsW, 12 + kt, lane);
      } else {
        const float* Wb = dw + (kt * 32 + 8 * q) * 16 + p;
        A[kt] = mk8(pk(Wb[0 * 16], Wb[1 * 16]), pk(Wb[2 * 16], Wb[3 * 16]),
                    pk(Wb[4 * 16], Wb[5 * 16]), pk(Wb[6 * 16], Wb[7 * 16]));
      }
    }
    f32x4 bi = *(const f32x4*)(db + 4 * q);
    #pragma unroll
    for (int nt = 0; nt < 4; ++nt) {
      bf16x8 B0 = bfrag_u<0>(uB[nt], q, p);
      bf16x8 B1 = bfrag_u<1>(uB[nt], q, p);
      f32x4 acc = mfma16(A[0], B0, bi);
      acc = mfma16(A[1], B1, acc);
      if (q == 0) {                 // g[0] = row 0 -> lane (0,p), acc.x
        int pt = ptb + nt * 16 + p;
        if (pt < N) outd[pt] = expf(acc.x - 1.0f);
      }
      g2[nt][0] = pk(acc.x, acc.y);
      g2[nt][1] = pk(acc.z, acc.w);
    }
  }

  { // L3: concat(g[1:16], sh16) -> 64, relu.  A = sets 14..17 (k-shifted cw0).
    bf16x8 A[4];
    #pragma unroll
    for (int mt = 0; mt < 4; ++mt) {
      if (PRE) {
        A[mt] = ld8(wsW, 14 + mt, lane);
      } else {
        float v[8];
        #pragma unroll
        for (int j = 0; j < 8; ++j) {
          int k = 8 * q + j;
          v[j] = (k == 0) ? 0.0f : cw0[(k - 1) * 64 + mt * 16 + p];
        }
        A[mt] = mk8(pk(v[0], v[1]), pk(v[2], v[3]), pk(v[4], v[5]), pk(v[6], v[7]));
      }
    }
    f32x4 bi[4];
    #pragma unroll
    for (int mt = 0; mt < 4; ++mt) bi[mt] = *(const f32x4*)(cb0 + mt * 16 + 4 * q);
    #pragma unroll
    for (int nt = 0; nt < 4; ++nt) {
      bf16x8 B = bfrag_cat(g2[nt], shp, nt * 16 + p, q, p);
      #pragma unroll
      for (int mt = 0; mt < 4; ++mt) {
        f32x4 acc = mfma16(A[mt], B, bi[mt]);
        acc.x = fmaxf(acc.x, 0.0f); acc.y = fmaxf(acc.y, 0.0f);
        acc.z = fmaxf(acc.z, 0.0f); acc.w = fmaxf(acc.w, 0.0f);
        uA[nt][mt][0] = pk(acc.x, acc.y);
        uA[nt][mt][1] = pk(acc.z, acc.w);
      }
    }
  }

  layer64<PRE, false>(cw1, wsW, 18, cb1, uA, uB, lane, q, p); // L4: 64->64
  layer64<PRE, false>(cw2, wsW, 26, cb2, uB, uA, lane, q, p); // L5: 64->64

  { // L6: 64 -> 3 (rw), sigmoid out.  A = sets 34..35 (rows >=3 zeroed).
    bf16x8 A[2];
    #pragma unroll
    for (int kt = 0; kt < 2; ++kt) {
      if (PRE) {
        A[kt] = ld8(wsW, 34 + kt, lane);
      } else {
        float v[8];
        #pragma unroll
        for (int j = 0; j < 8; ++j) {
          int k = kt * 32 + 8 * q + j;
          v[j] = (p < 3) ? rw[k * 3 + p] : 0.0f;
        }
        A[kt] = mk8(pk(v[0], v[1]), pk(v[2], v[3]), pk(v[4], v[5]), pk(v[6], v[7]));
      }
    }
    float r0 = rb[0], r1 = rb[1], r2 = rb[2];
    #pragma unroll
    for (int nt = 0; nt < 4; ++nt) {
      bf16x8 B0 = bfrag_u<0>(uA[nt], q, p);
      bf16x8 B1 = bfrag_u<1>(uA[nt], q, p);
      f32x4 acc;
      acc.x = (q == 0) ? r0 : 0.0f;
      acc.y = (q == 0) ? r1 : 0.0f;
      acc.z = (q == 0) ? r2 : 0.0f;
      acc.w = 0.0f;
      acc = mfma16(A[0], B0, acc);
      acc = mfma16(A[1], B1, acc);
      if (q == 0) {                 // rgb = rows 0..2 -> lane (0,p): acc.x/y/z
        int pt = ptb + nt * 16 + p;
        if (pt < N) {
          outrgb[3 * pt + 0] = 1.0f / (1.0f + expf(-acc.x));
          outrgb[3 * pt + 1] = 1.0f / (1.0f + expf(-acc.y));
          outrgb[3 * pt + 2] = 1.0f / (1.0f + expf(-acc.z));
        }
      }
    }
  }
}

extern "C" void kernel_launch(void* const* d_in, const int* in_sizes, int n_in,
                              void* d_out, int out_size, void* d_ws, size_t ws_size,
                              hipStream_t stream) {
  const float* pos  = (const float*)d_in[0];
  const float* dirs = (const float*)d_in[1];
  const float* emb  = (const float*)d_in[2];
  const float* gw0  = (const float*)d_in[3];
  const float* gb0  = (const float*)d_in[4];
  const float* gw1  = (const float*)d_in[5];
  const float* gb1  = (const float*)d_in[6];
  const float* dw   = (const float*)d_in[7];
  const float* db   = (const float*)d_in[8];
  const float* cw0  = (const float*)d_in[9];
  const float* cb0  = (const float*)d_in[10];
  const float* cw1  = (const float*)d_in[11];
  const float* cb1  = (const float*)d_in[12];
  const float* cw2  = (const float*)d_in[13];
  const float* cb2  = (const float*)d_in[14];
  const float* rw   = (const float*)d_in[15];
  const float* rb   = (const float*)d_in[16];

  const int N = in_sizes[0] / 3;
  float* outd   = (float*)d_out;
  float* outrgb = outd + N;

  const size_t need = (size_t)(16 * TT) * 4 + (size_t)(WSETS * 64) * 16; // 299008 B
  const bool pre = (ws_size >= need);
  unsigned* wsTab = (unsigned*)d_ws;

  const int grid = (N + BLK - 1) / BLK;
  if (pre) {
    const int packN = 16 * TT + WSETS * 64;
    hipLaunchKernelGGL(ngp_pack, dim3((packN + 255) / 256), dim3(256), 0, stream,
                       emb, gw0, gw1, dw, cw0, cw1, cw2, rw, wsTab);
    hipLaunchKernelGGL((ngp_fused9<true>), dim3(grid), dim3(BLK), 0, stream,
                       pos, dirs, emb, wsTab, gw0, gb0, gw1, gb1, dw, db,
                       cw0, cb0, cw1, cb1, cw2, cb2, rw, rb, outd, outrgb, N);
  } else {
    hipLaunchKernelGGL((ngp_fused9<false>), dim3(grid), dim3(BLK), 0, stream,
                       pos, dirs, emb, wsTab, gw0, gb0, gw1, gb1, dw, db,
                       cw0, cb0, cw1, cb1, cw2, cb2, rw, rb, outd, outrgb, N);
  }
}